// Round 5
// baseline (578.554 us; speedup 1.0000x reference)
//
#include <hip/hip_runtime.h>
#include <hip/hip_bf16.h>

// RNN: B=1024, T=512, H=128, +4 autoregressive steps -> out (1024, 516)
// Round 5: interleave G=2 independent batch groups per block so the serial
// chain + barrier drain of one group hides behind the other group's issue.
//  - 32 blocks x 256 thr; block owns 32 batch rows = 2 groups of 16.
//  - per macro-step each wave: B-frags(g0,g1) -> MFMA(g0) -> MFMA(g1) ->
//    epilogues -> h writes -> ONE barrier. W frags shared across groups.
//  - y deferred via LDS pq; on-chain feedback only for the 5 tail steps.
//  - no global memory ops inside the loop; x in LDS, y flushed at end.

#define BB 1024
#define TT 512
#define HH 128
#define TOUT 516
#define BM 16          // batch rows per group
#define G 2            // groups per block
#define NW 4           // waves per block
#define MTW 2          // 16-row m-tiles per wave (4*2*16 = 128 = HH)
#define HSTR 136       // padded h stride in bf16 (272 B = 17 x 16B)
#define XSTR 513       // xs stride (dwords), 513 % 32 == 1
#define YSTR 517       // ybuf stride (dwords), 517 % 32 == 5 (odd)

typedef __attribute__((ext_vector_type(8))) short bf16x8;
typedef __attribute__((ext_vector_type(4))) short short4_t;
typedef __attribute__((ext_vector_type(4))) float f32x4;

__device__ __forceinline__ short f2bs(float f) {
    __hip_bfloat16 h = __float2bfloat16(f);
    return __builtin_bit_cast(short, h);
}
__device__ __forceinline__ float bs2f(short s) {
    __hip_bfloat16 h = __builtin_bit_cast(__hip_bfloat16, s);
    return __bfloat162float(h);
}

__global__ void detect_dtype(const void* w, int* flag) {
    const int lane = threadIdx.x;  // 64 threads
    const __hip_bfloat16* p = (const __hip_bfloat16*)w;
    const float v0 = __bfloat162float(p[lane]);
    const float v1 = __bfloat162float(p[64 + lane]);
    const bool bad = !(fabsf(v0) < 100.0f) || !(fabsf(v1) < 100.0f);
    const unsigned long long m = __ballot(bad);
    if (lane == 0) *flag = (__popcll(m) > 4) ? 1 : 0;  // 1 => data is fp32
}

template <bool F32>
__device__ __forceinline__ float ldg(const void* p, int idx) {
    if (F32) return ((const float*)p)[idx];
    return __bfloat162float(((const __hip_bfloat16*)p)[idx]);
}

template <bool F32>
__device__ void rnn_body(const void* __restrict__ xg, const void* __restrict__ h0,
                         const void* __restrict__ w0, const void* __restrict__ b0,
                         const void* __restrict__ W,  const void* __restrict__ bw,
                         const void* __restrict__ dw, const void* __restrict__ db,
                         void* __restrict__ out,
                         float (*xs)[XSTR], float (*ybuf)[YSTR],
                         __hip_bfloat16 (*hbuf)[2][BM][HSTR], float (*pq)[2][BM][4])
{
    const int tid  = threadIdx.x;
    const int lane = tid & 63;
    const int wv   = tid >> 6;        // 0..3
    const int q    = lane >> 4;       // 0..3
    const int n    = lane & 15;       // batch col within group
    const int row0 = blockIdx.x * (G * BM);

    // stage x (fp32 in LDS): xs[g*BM+rr][t]
    for (int idx = tid; idx < G * BM * TT; idx += 256) {
        const int rg = idx >> 9, t2 = idx & (TT - 1);
        xs[rg][t2] = ldg<F32>(xg, (row0 + rg) * TT + t2);
    }
    // stage h0 as bf16
    for (int idx = tid; idx < G * BM * HH; idx += 256) {
        const int g = idx >> 11, rr = (idx >> 7) & (BM - 1), ii = idx & (HH - 1);
        hbuf[g][0][rr][ii] = __float2bfloat16(ldg<F32>(h0, (row0 + g * BM + rr) * HH + ii));
    }

    // preload W fragments (A-operand: A[m=lane&15][k=q*8+j]), hi/lo split
    bf16x8 wa_hi[MTW][4], wa_lo[MTW][4];
    #pragma unroll
    for (int m2 = 0; m2 < MTW; ++m2) {
        const int ia = (wv * MTW + m2) * 16 + n;           // W row (output unit)
        #pragma unroll
        for (int kf = 0; kf < 4; ++kf) {
            const int kb = kf * 32 + q * 8;
            bf16x8 hi, lo;
            #pragma unroll
            for (int j = 0; j < 8; ++j) {
                const float f = ldg<F32>(W, ia * HH + kb + j);
                const short hs = f2bs(f);
                hi[j] = hs;
                lo[j] = F32 ? f2bs(f - bs2f(hs)) : (short)0;
            }
            wa_hi[m2][kf] = hi;
            wa_lo[m2][kf] = lo;
        }
    }
    // epilogue constants (C-layout rows: i = (wv*MTW+m2)*16 + q*4 + r)
    float bsum[MTW][4], w0v[MTW][4], decv[MTW][4];
    #pragma unroll
    for (int m2 = 0; m2 < MTW; ++m2)
        #pragma unroll
        for (int r = 0; r < 4; ++r) {
            const int ic = (wv * MTW + m2) * 16 + q * 4 + r;
            bsum[m2][r] = ldg<F32>(b0, ic) + ldg<F32>(bw, ic);
            w0v[m2][r]  = ldg<F32>(w0, ic);
            decv[m2][r] = ldg<F32>(dw, ic);
        }
    const float dbv = ldg<F32>(db, 0);

    __syncthreads();

    int cur = 0;
    float xpref[G];
    #pragma unroll
    for (int g = 0; g < G; ++g) xpref[g] = xs[g * BM + n][0];

    #pragma unroll 1
    for (int t = 0; t < TOUT; ++t) {
        // B-fragments for BOTH groups first (longest-latency loads)
        bf16x8 bfrag[G][4];
        #pragma unroll
        for (int g = 0; g < G; ++g)
            #pragma unroll
            for (int kf = 0; kf < 4; ++kf)
                bfrag[g][kf] = *(const bf16x8*)&hbuf[g][cur][n][kf * 32 + q * 8];

        // step inputs
        float xv[G];
        #pragma unroll
        for (int g = 0; g < G; ++g) {
            if (t < TT) {
                xv[g] = xpref[g];
            } else {  // tail feedback: y[t-1] on-chain (5 steps only)
                const f32x4 v = *(const f32x4*)&pq[g][(t - 1) & 1][n][0];
                xv[g] = v[0] + v[1] + v[2] + v[3] + dbv;
            }
        }
        #pragma unroll
        for (int g = 0; g < G; ++g)
            if (t + 1 < TT) xpref[g] = xs[g * BM + n][t + 1];

        // deferred y writer (off-chain): wave g, q==0 lanes emit y[t-1]
        if (q == 0 && wv < G && t > 0) {
            const f32x4 v = *(const f32x4*)&pq[wv][(t - 1) & 1][n][0];
            ybuf[wv * BM + n][t - 1] = v[0] + v[1] + v[2] + v[3] + dbv;
        }

        #pragma unroll
        for (int g = 0; g < G; ++g) {
            // acc[m2][hf]: hi+lo share an accumulator; bias+x folded into init
            f32x4 acc[MTW][2];
            #pragma unroll
            for (int m2 = 0; m2 < MTW; ++m2) {
                #pragma unroll
                for (int r = 0; r < 4; ++r)
                    acc[m2][0][r] = fmaf(xv[g], w0v[m2][r], bsum[m2][r]);
                acc[m2][1] = (f32x4){0.f, 0.f, 0.f, 0.f};
            }
            #pragma unroll
            for (int kf = 0; kf < 4; ++kf) {
                const int hf = kf >> 1;
                #pragma unroll
                for (int m2 = 0; m2 < MTW; ++m2) {
                    acc[m2][hf] = __builtin_amdgcn_mfma_f32_16x16x32_bf16(
                        wa_hi[m2][kf], bfrag[g][kf], acc[m2][hf], 0, 0, 0);
                    if (F32)
                        acc[m2][hf] = __builtin_amdgcn_mfma_f32_16x16x32_bf16(
                            wa_lo[m2][kf], bfrag[g][kf], acc[m2][hf], 0, 0, 0);
                }
            }
            // epilogue: z -> tanh -> pack bf16 -> decoder partial
            float p = 0.0f;
            #pragma unroll
            for (int m2 = 0; m2 < MTW; ++m2) {
                short4_t pk;
                #pragma unroll
                for (int r = 0; r < 4; ++r) {
                    const float z = acc[m2][0][r] + acc[m2][1][r];
                    const float e = __expf(z + z);
                    const float h = 1.0f - 2.0f * __builtin_amdgcn_rcpf(e + 1.0f);
                    p = fmaf(decv[m2][r], h, p);
                    pk[r] = f2bs(h);
                }
                *(short4_t*)&hbuf[g][cur ^ 1][n][(wv * MTW + m2) * 16 + q * 4] = pk;
            }
            p += __shfl_xor(p, 16);
            p += __shfl_xor(p, 32);
            if (q == 0) pq[g][t & 1][n][wv] = p;
        }
        __syncthreads();
        cur ^= 1;
    }

    // tail: y[TOUT-1]
    if (q == 0 && wv < G) {
        const f32x4 v = *(const f32x4*)&pq[wv][(TOUT - 1) & 1][n][0];
        ybuf[wv * BM + n][TOUT - 1] = v[0] + v[1] + v[2] + v[3] + dbv;
    }
    __syncthreads();

    // flush outputs (coalesced over t)
    for (int rg = 0; rg < G * BM; ++rg)
        for (int t2 = tid; t2 < TOUT; t2 += 256) {
            const int o = (row0 + rg) * TOUT + t2;
            const float y = ybuf[rg][t2];
            if (F32) ((float*)out)[o] = y;
            else     ((__hip_bfloat16*)out)[o] = __float2bfloat16(y);
        }
}

__global__ __launch_bounds__(256, 1)
void rnn_mfma(const void* __restrict__ xg, const void* __restrict__ h0,
              const void* __restrict__ w0, const void* __restrict__ b0,
              const void* __restrict__ W,  const void* __restrict__ bw,
              const void* __restrict__ dw, const void* __restrict__ db,
              void* __restrict__ out, const int* __restrict__ flag)
{
    __shared__ float xs[G * BM][XSTR];                         // 65.7 KB
    __shared__ float ybuf[G * BM][YSTR];                       // 66.2 KB
    __shared__ __align__(16) __hip_bfloat16 hbuf[G][2][BM][HSTR]; // 17.4 KB
    __shared__ __align__(16) float pq[G][2][BM][4];            // 1 KB

    const int f = *(volatile const int*)flag;  // block-uniform
    if (f) rnn_body<true >(xg, h0, w0, b0, W, bw, dw, db, out, xs, ybuf, hbuf, pq);
    else   rnn_body<false>(xg, h0, w0, b0, W, bw, dw, db, out, xs, ybuf, hbuf, pq);
}

extern "C" void kernel_launch(void* const* d_in, const int* in_sizes, int n_in,
                              void* d_out, int out_size, void* d_ws, size_t ws_size,
                              hipStream_t stream) {
    int* flag = (int*)d_ws;
    detect_dtype<<<1, 64, 0, stream>>>(d_in[4], flag);  // probe fc_w
    rnn_mfma<<<BB / (G * BM), 256, 0, stream>>>(d_in[0], d_in[1], d_in[2], d_in[3],
                                                d_in[4], d_in[5], d_in[6], d_in[7],
                                                d_out, flag);
}

// Round 6
// 334.105 us; speedup vs baseline: 1.7317x; 1.7317x over previous
//
#include <hip/hip_runtime.h>
#include <hip/hip_bf16.h>

// RNN: B=1024, T=512, H=128, +4 autoregressive steps -> out (1024, 516)
// Round 6: minimal serial chain. G=1 (64 blocks x 256 thr), known-good R3
// structure, with every off-chain opportunity taken:
//  - NO shfl on chain: each lane writes its decoder partial to pq (1 b32
//    write); 16-way reduce done OFF-chain next step by wave 3 (-> ybuf).
//    On-chain reduce only for the 5 tail feedback steps.
//  - ONE barrier per step (pq parity double-buffered).
//  - xs[t+1] read issued at step top, consumed next step (off-chain).
//  - bias + x*w0 folded into MFMA accumulator init.
//  - no global memory ops in the loop; y flushed from LDS at the end.

#define BB 1024
#define TT 512
#define HH 128
#define TOUT 516
#define BM 16          // batch rows per block
#define MTW 2          // 16-row m-tiles per wave (4 waves * 2 * 16 = 128)
#define HSTR 136       // h stride in bf16 (272 B)
#define XSTR 513       // xs stride (dwords)
#define YSTR 517       // ybuf stride (dwords)
#define PQS 20         // pq row stride (dwords): 80 B, 16B-aligned

typedef __attribute__((ext_vector_type(8))) short bf16x8;
typedef __attribute__((ext_vector_type(4))) short short4_t;
typedef __attribute__((ext_vector_type(4))) float f32x4;

__device__ __forceinline__ short f2bs(float f) {
    __hip_bfloat16 h = __float2bfloat16(f);
    return __builtin_bit_cast(short, h);
}
__device__ __forceinline__ float bs2f(short s) {
    __hip_bfloat16 h = __builtin_bit_cast(__hip_bfloat16, s);
    return __bfloat162float(h);
}

__global__ void detect_dtype(const void* w, int* flag) {
    const int lane = threadIdx.x;  // 64 threads
    const __hip_bfloat16* p = (const __hip_bfloat16*)w;
    const float v0 = __bfloat162float(p[lane]);
    const float v1 = __bfloat162float(p[64 + lane]);
    const bool bad = !(fabsf(v0) < 100.0f) || !(fabsf(v1) < 100.0f);
    const unsigned long long m = __ballot(bad);
    if (lane == 0) *flag = (__popcll(m) > 4) ? 1 : 0;  // 1 => data is fp32
}

template <bool F32>
__device__ __forceinline__ float ldg(const void* p, int idx) {
    if (F32) return ((const float*)p)[idx];
    return __bfloat162float(((const __hip_bfloat16*)p)[idx]);
}

// sum of pq[par][n][0..15] (16B-aligned rows)
__device__ __forceinline__ float red16(const float* pqrow) {
    const f32x4* pr = (const f32x4*)pqrow;
    const f32x4 s = (pr[0] + pr[1]) + (pr[2] + pr[3]);
    return (s[0] + s[1]) + (s[2] + s[3]);
}

template <bool F32>
__device__ void rnn_body(const void* __restrict__ xg, const void* __restrict__ h0,
                         const void* __restrict__ w0, const void* __restrict__ b0,
                         const void* __restrict__ W,  const void* __restrict__ bw,
                         const void* __restrict__ dw, const void* __restrict__ db,
                         void* __restrict__ out,
                         float (*xs)[XSTR], float (*ybuf)[YSTR],
                         __hip_bfloat16 (*hbuf)[BM][HSTR], float (*pq)[BM][PQS])
{
    const int tid  = threadIdx.x;
    const int lane = tid & 63;
    const int wv   = tid >> 6;        // 0..3
    const int q    = lane >> 4;       // 0..3
    const int n    = lane & 15;       // batch col
    const int row0 = blockIdx.x * BM;

    // stage x (fp32 in LDS)
    for (int idx = tid; idx < BM * TT; idx += 256) {
        const int rr = idx >> 9, t2 = idx & (TT - 1);
        xs[rr][t2] = ldg<F32>(xg, (row0 + rr) * TT + t2);
    }
    // stage h0 as bf16
    for (int idx = tid; idx < BM * HH; idx += 256) {
        const int rr = idx >> 7, ii = idx & (HH - 1);
        hbuf[0][rr][ii] = __float2bfloat16(ldg<F32>(h0, (row0 + rr) * HH + ii));
    }

    // preload W fragments (A-operand: A[m=lane&15][k=q*8+j]), hi/lo split
    bf16x8 wa_hi[MTW][4], wa_lo[MTW][4];
    #pragma unroll
    for (int m2 = 0; m2 < MTW; ++m2) {
        const int ia = (wv * MTW + m2) * 16 + n;           // W row (output unit)
        #pragma unroll
        for (int kf = 0; kf < 4; ++kf) {
            const int kb = kf * 32 + q * 8;
            bf16x8 hi, lo;
            #pragma unroll
            for (int j = 0; j < 8; ++j) {
                const float f = ldg<F32>(W, ia * HH + kb + j);
                const short hs = f2bs(f);
                hi[j] = hs;
                lo[j] = F32 ? f2bs(f - bs2f(hs)) : (short)0;
            }
            wa_hi[m2][kf] = hi;
            wa_lo[m2][kf] = lo;
        }
    }
    // epilogue constants (C-layout rows: i = (wv*MTW+m2)*16 + q*4 + r)
    float bsum[MTW][4], w0v[MTW][4], decv[MTW][4];
    #pragma unroll
    for (int m2 = 0; m2 < MTW; ++m2)
        #pragma unroll
        for (int r = 0; r < 4; ++r) {
            const int ic = (wv * MTW + m2) * 16 + q * 4 + r;
            bsum[m2][r] = ldg<F32>(b0, ic) + ldg<F32>(bw, ic);
            w0v[m2][r]  = ldg<F32>(w0, ic);
            decv[m2][r] = ldg<F32>(dw, ic);
        }
    const float dbv = ldg<F32>(db, 0);

    __syncthreads();

    int cur = 0;
    float xpref = xs[n][0];
    #pragma unroll 1
    for (int t = 0; t < TOUT; ++t) {
        const int par  = t & 1;
        const int par1 = (t - 1) & 1;

        // B-fragments first (longest-latency on-chain loads)
        bf16x8 bfrag[4];
        #pragma unroll
        for (int kf = 0; kf < 4; ++kf)
            bfrag[kf] = *(const bf16x8*)&hbuf[cur][n][kf * 32 + q * 8];

        // next step's x (consumed next iter -> latency fully hidden)
        float xnext = 0.0f;
        if (t + 1 < TT) xnext = xs[n][t + 1];

        // OFF-chain deferred y writer: wave 3 emits y[t-1] from pq partials
        if (wv == 3 && q == 0 && t > 0)
            ybuf[n][t - 1] = red16(&pq[par1][n][0]) + dbv;

        // step input: prefetched x, or tail feedback (on-chain, 5 steps only)
        float xv;
        if (t < TT) xv = xpref;
        else        xv = red16(&pq[par1][n][0]) + dbv;

        // MFMA: acc0 init = bias + x*w0 ; two chains (kf halves), hi+lo shared
        f32x4 acc[MTW][2];
        #pragma unroll
        for (int m2 = 0; m2 < MTW; ++m2) {
            #pragma unroll
            for (int r = 0; r < 4; ++r)
                acc[m2][0][r] = fmaf(xv, w0v[m2][r], bsum[m2][r]);
            acc[m2][1] = (f32x4){0.f, 0.f, 0.f, 0.f};
        }
        #pragma unroll
        for (int kf = 0; kf < 4; ++kf) {
            const int hf = kf >> 1;
            #pragma unroll
            for (int m2 = 0; m2 < MTW; ++m2) {
                acc[m2][hf] = __builtin_amdgcn_mfma_f32_16x16x32_bf16(
                    wa_hi[m2][kf], bfrag[kf], acc[m2][hf], 0, 0, 0);
                if (F32)
                    acc[m2][hf] = __builtin_amdgcn_mfma_f32_16x16x32_bf16(
                        wa_lo[m2][kf], bfrag[kf], acc[m2][hf], 0, 0, 0);
            }
        }

        // epilogue: z -> tanh -> pack bf16 -> private decoder partial
        float p = 0.0f;
        #pragma unroll
        for (int m2 = 0; m2 < MTW; ++m2) {
            short4_t pk;
            #pragma unroll
            for (int r = 0; r < 4; ++r) {
                const float z = acc[m2][0][r] + acc[m2][1][r];
                const float e = __expf(z + z);
                const float h = 1.0f - 2.0f * __builtin_amdgcn_rcpf(e + 1.0f);
                p = fmaf(decv[m2][r], h, p);
                pk[r] = f2bs(h);
            }
            *(short4_t*)&hbuf[cur ^ 1][n][(wv * MTW + m2) * 16 + q * 4] = pk;
        }
        // every lane writes its own partial: NO on-chain reduction
        pq[par][n][wv * 4 + q] = p;

        xpref = xnext;
        __syncthreads();
        cur ^= 1;
    }

    // tail: y[TOUT-1]
    if (wv == 3 && q == 0)
        ybuf[n][TOUT - 1] = red16(&pq[(TOUT - 1) & 1][n][0]) + dbv;
    __syncthreads();

    // flush outputs (coalesced over t)
    for (int rr = 0; rr < BM; ++rr)
        for (int t2 = tid; t2 < TOUT; t2 += 256) {
            const int o = (row0 + rr) * TOUT + t2;
            const float y = ybuf[rr][t2];
            if (F32) ((float*)out)[o] = y;
            else     ((__hip_bfloat16*)out)[o] = __float2bfloat16(y);
        }
}

__global__ __launch_bounds__(256, 1)
void rnn_mfma(const void* __restrict__ xg, const void* __restrict__ h0,
              const void* __restrict__ w0, const void* __restrict__ b0,
              const void* __restrict__ W,  const void* __restrict__ bw,
              const void* __restrict__ dw, const void* __restrict__ db,
              void* __restrict__ out, const int* __restrict__ flag)
{
    __shared__ float xs[BM][XSTR];                          // 32.8 KB
    __shared__ float ybuf[BM][YSTR];                        // 33.1 KB
    __shared__ __align__(16) __hip_bfloat16 hbuf[2][BM][HSTR]; // 8.7 KB
    __shared__ __align__(16) float pq[2][BM][PQS];          // 2.6 KB

    const int f = *(volatile const int*)flag;  // block-uniform
    if (f) rnn_body<true >(xg, h0, w0, b0, W, bw, dw, db, out, xs, ybuf, hbuf, pq);
    else   rnn_body<false>(xg, h0, w0, b0, W, bw, dw, db, out, xs, ybuf, hbuf, pq);
}

extern "C" void kernel_launch(void* const* d_in, const int* in_sizes, int n_in,
                              void* d_out, int out_size, void* d_ws, size_t ws_size,
                              hipStream_t stream) {
    int* flag = (int*)d_ws;
    detect_dtype<<<1, 64, 0, stream>>>(d_in[4], flag);  // probe fc_w
    rnn_mfma<<<BB / BM, 256, 0, stream>>>(d_in[0], d_in[1], d_in[2], d_in[3],
                                          d_in[4], d_in[5], d_in[6], d_in[7],
                                          d_out, flag);
}